// Round 6
// baseline (252.009 us; speedup 1.0000x reference)
//
#include <hip/hip_runtime.h>

#define B_   8
#define C_   512
#define HW_  1024
#define NCOL (B_*HW_)   /* 8192 */
#define NROWS 192
#define EPS  1e-5f
#define NBLK 256
#define NCHUNK 32

/* ws layout (float offsets) */
#define YOFF   0
#define YSZ    (NROWS*NCOL)            /* 1,572,864 */
#define WOFF   (YOFF+YSZ)              /* W hi/lo u16: 98,304 floats */
#define WSZ    98304
#define SPOFF  (WOFF+WSZ)              /* stats partials [128][2][2] */
#define SPSZ   512
#define CTROFF (SPOFF+SPSZ)            /* barrier counter */
#define CTRSZ  16
#define CP2OFF (CTROFF+CTRSZ)          /* partials [8][3][32][4096] */
#define CP2SZ  (B_*3*NCHUNK*4096)
#define CMOFF  (CP2OFF+CP2SZ)          /* reduced [24][4096] */
#define CMSZ   (24*4096)
#define ISOFF  (CMOFF+CMSZ)            /* inv sigma [8] pad 16 */
#define UOFF   (ISOFF+16)              /* U [8][512][64] */

typedef unsigned short u16;
typedef __attribute__((ext_vector_type(8))) short short8;
typedef __attribute__((ext_vector_type(4))) float f32x4;

__device__ __forceinline__ u16 f2bf(float f) {
  unsigned u = __float_as_uint(f);
  unsigned r = u + 0x7fffu + ((u >> 16) & 1u);
  return (u16)(r >> 16);
}
__device__ __forceinline__ float bf2f(u16 h) {
  return __uint_as_float(((unsigned)h) << 16);
}
#define MFMA_B16(a,b,c) __builtin_amdgcn_mfma_f32_16x16x32_bf16(a,b,c,0,0,0)

#define FMA16(a, bb) \
  acc[0][0]+=a.x*bb.x; acc[0][1]+=a.x*bb.y; acc[0][2]+=a.x*bb.z; acc[0][3]+=a.x*bb.w; \
  acc[1][0]+=a.y*bb.x; acc[1][1]+=a.y*bb.y; acc[1][2]+=a.y*bb.z; acc[1][3]+=a.y*bb.w; \
  acc[2][0]+=a.z*bb.x; acc[2][1]+=a.z*bb.y; acc[2][2]+=a.z*bb.z; acc[2][3]+=a.z*bb.w; \
  acc[3][0]+=a.w*bb.x; acc[3][1]+=a.w*bb.y; acc[3][2]+=a.w*bb.z; acc[3][3]+=a.w*bb.w;

union alignas(16) SMem {
  struct { u16 Xh[8*32*8]; u16 Xl[8*32*8]; } conv;                       /* 8 KB  */
  struct { u16 Sh[3][64][40]; u16 Sl[3][64][40]; float sc[128]; float sf[128]; } cpart; /* 31.7 KB */
  struct { float sh[256]; float sh2[256]; } stats;                       /* 2 KB  */
  struct { float v[64]; float u[64]; } sigma;                            /* 0.5KB */
  struct { float Tl[64][64]; } ufold;                                    /* 16 KB */
  struct { float Ut[64][64]; float Fl[64][64]; float scF[64]; float sfF[64]; } fin; /* 33 KB */
};

/* agent-scope grid barrier; counter pre-zeroed by k_init each launch */
__device__ __forceinline__ void gbar(unsigned* ctr, unsigned phase) {
  __syncthreads();
  if (threadIdx.x == 0) {
    __hip_atomic_fetch_add(ctr, 1u, __ATOMIC_ACQ_REL, __HIP_MEMORY_SCOPE_AGENT);
    const unsigned tgt = (unsigned)NBLK * (phase + 1u);
    while (__hip_atomic_load(ctr, __ATOMIC_ACQUIRE, __HIP_MEMORY_SCOPE_AGENT) < tgt)
      __builtin_amdgcn_s_sleep(4);
  }
  __syncthreads();
  __builtin_amdgcn_fence(__ATOMIC_ACQUIRE, "agent");
}

__global__ void k_init(float* __restrict__ ws) {
  if (threadIdx.x == 0) *reinterpret_cast<unsigned*>(ws + CTROFF) = 0u;
}

__global__ __launch_bounds__(256, 2) void k_mega(
    const float* __restrict__ x,
    const float* __restrict__ Wf, const float* __restrict__ bf,
    const float* __restrict__ gamma_f, const float* __restrict__ beta_f,
    const float* __restrict__ Wg, const float* __restrict__ bg,
    const float* __restrict__ gamma_g, const float* __restrict__ beta_g,
    const float* __restrict__ Wh, const float* __restrict__ bh,
    const float* __restrict__ Wv, const float* __restrict__ bv,
    float* __restrict__ out, float* __restrict__ ws)
{
  __shared__ SMem sm;
  const int bid = blockIdx.x;
  const int t = threadIdx.x;
  unsigned* ctr = reinterpret_cast<unsigned*>(ws + CTROFF);
  u16* Whi = (u16*)(ws + WOFF);
  u16* Wlo = Whi + NROWS*C_;

  /* ---------- P0: W split into bf16 hi/lo ---------- */
  {
    const int e4 = bid*256 + t;
    if (e4 < NROWS*C_/4) {
      const int e = e4*4;
      const int row = e >> 9, k = e & 511;
      const float* src = (row < 64) ? &Wf[row*C_ + k]
                       : (row < 128) ? &Wg[(row-64)*C_ + k]
                       : &Wh[(row-128)*C_ + k];
      const float4 v = *reinterpret_cast<const float4*>(src);
      u16 h0=f2bf(v.x), h1=f2bf(v.y), h2=f2bf(v.z), h3=f2bf(v.w);
      u16 l0=f2bf(v.x-bf2f(h0)), l1=f2bf(v.y-bf2f(h1)), l2=f2bf(v.z-bf2f(h2)), l3=f2bf(v.w-bf2f(h3));
      uint2 ph; ph.x = (unsigned)h0 | ((unsigned)h1<<16); ph.y = (unsigned)h2 | ((unsigned)h3<<16);
      uint2 pl; pl.x = (unsigned)l0 | ((unsigned)l1<<16); pl.y = (unsigned)l2 | ((unsigned)l3<<16);
      *reinterpret_cast<uint2*>(&Whi[e]) = ph;
      *reinterpret_cast<uint2*>(&Wlo[e]) = pl;
    }
  }
  gbar(ctr, 0);

  /* ---------- P1: Y = W @ X + bias (MFMA bf16x3), 32-col tile per block ---------- */
  {
    const int n0  = bid * 32;
    const int b   = n0 >> 10;
    const int hw0 = n0 & 1023;
    const int lane = t & 63, wid = t >> 6;
    const int wrow0 = wid * 48;
    const int cst = t & 31, kg2 = t >> 5;
    const int lm = lane & 15, lk = lane >> 4;

    f32x4 acc[3][2];
    #pragma unroll
    for (int i=0;i<3;++i) { acc[i][0]=(f32x4)0.f; acc[i][1]=(f32x4)0.f; }

    for (int kk = 0; kk < C_; kk += 64) {
      __syncthreads();
      {
        const float* xp = x + ((size_t)(b*C_ + kk + kg2*8))*HW_ + hw0 + cst;
        u16 hb[8], lb[8];
        #pragma unroll
        for (int i=0;i<8;++i) {
          const float v = xp[(size_t)i*HW_];
          hb[i] = f2bf(v); lb[i] = f2bf(v - bf2f(hb[i]));
        }
        uint4 ph, pl;
        ph.x=(unsigned)hb[0]|((unsigned)hb[1]<<16); ph.y=(unsigned)hb[2]|((unsigned)hb[3]<<16);
        ph.z=(unsigned)hb[4]|((unsigned)hb[5]<<16); ph.w=(unsigned)hb[6]|((unsigned)hb[7]<<16);
        pl.x=(unsigned)lb[0]|((unsigned)lb[1]<<16); pl.y=(unsigned)lb[2]|((unsigned)lb[3]<<16);
        pl.z=(unsigned)lb[4]|((unsigned)lb[5]<<16); pl.w=(unsigned)lb[6]|((unsigned)lb[7]<<16);
        *reinterpret_cast<uint4*>(&sm.conv.Xh[(kg2*32+cst)*8]) = ph;
        *reinterpret_cast<uint4*>(&sm.conv.Xl[(kg2*32+cst)*8]) = pl;
      }
      __syncthreads();
      #pragma unroll
      for (int kb = 0; kb < 2; ++kb) {
        short8 bhf[2], blf[2];
        #pragma unroll
        for (int nt = 0; nt < 2; ++nt) {
          const int col = nt*16 + lm;
          const int idx = ((kb*4 + lk)*32 + col)*8;
          bhf[nt] = *reinterpret_cast<const short8*>(&sm.conv.Xh[idx]);
          blf[nt] = *reinterpret_cast<const short8*>(&sm.conv.Xl[idx]);
        }
        #pragma unroll
        for (int mt = 0; mt < 3; ++mt) {
          const int row = wrow0 + mt*16 + lm;
          const size_t widx = (size_t)row*C_ + kk + kb*32 + lk*8;
          const short8 ah = *reinterpret_cast<const short8*>(&Whi[widx]);
          const short8 al = *reinterpret_cast<const short8*>(&Wlo[widx]);
          #pragma unroll
          for (int nt = 0; nt < 2; ++nt) {
            acc[mt][nt] = MFMA_B16(ah, bhf[nt], acc[mt][nt]);
            acc[mt][nt] = MFMA_B16(al, bhf[nt], acc[mt][nt]);
            acc[mt][nt] = MFMA_B16(ah, blf[nt], acc[mt][nt]);
          }
        }
      }
    }
    #pragma unroll
    for (int mt = 0; mt < 3; ++mt) {
      const int rbase = wrow0 + mt*16;
      const float* bp = (rbase < 64) ? bf : (rbase < 128) ? bg : bh;
      const int rloc0 = (rbase & 63) + lk*4;
      #pragma unroll
      for (int nt = 0; nt < 2; ++nt) {
        const int col = n0 + nt*16 + lm;
        #pragma unroll
        for (int r = 0; r < 4; ++r) {
          const int row = rbase + lk*4 + r;
          ws[YOFF + (size_t)row*NCOL + col] = acc[mt][nt][r] + bp[rloc0 + r];
        }
      }
    }
  }
  gbar(ctr, 1);

  /* ---------- P2: stats partials, half-row per block ---------- */
  {
    const int row = bid >> 1, half = bid & 1;
    const float4* Yr = reinterpret_cast<const float4*>(ws + YOFF + (size_t)row*NCOL + half*4096);
    float s = 0.f, s2 = 0.f;
    for (int q = t; q < 1024; q += 256) {
      const float4 v = Yr[q];
      s  += (v.x+v.y)+(v.z+v.w);
      s2 += (v.x*v.x+v.y*v.y)+(v.z*v.z+v.w*v.w);
    }
    sm.stats.sh[t] = s; sm.stats.sh2[t] = s2;
    __syncthreads();
    for (int st = 128; st > 0; st >>= 1) {
      if (t < st) { sm.stats.sh[t] += sm.stats.sh[t+st]; sm.stats.sh2[t] += sm.stats.sh2[t+st]; }
      __syncthreads();
    }
    if (t == 0) {
      ws[SPOFF + row*4 + half*2 + 0] = sm.stats.sh[0];
      ws[SPOFF + row*4 + half*2 + 1] = sm.stats.sh2[0];
    }
  }
  gbar(ctr, 2);

  /* ---------- P3: Cf/Cg/T partials, 32-col chunk per block ---------- */
  {
    const int chunk = bid & 31, b = bid >> 5;
    if (t < 128) {
      const float* sp = ws + SPOFF;
      const float s  = sp[t*4+0] + sp[t*4+2];
      const float s2 = sp[t*4+1] + sp[t*4+3];
      const float mean = s*(1.0f/NCOL);
      const float var  = s2*(1.0f/NCOL) - mean*mean;
      const float g  = (t < 64) ? gamma_f[t] : gamma_g[t-64];
      const float be = (t < 64) ? beta_f[t]  : beta_g[t-64];
      const float sc = g * rsqrtf(var + EPS);
      sm.cpart.sc[t] = sc; sm.cpart.sf[t] = be - mean*sc;
    }
    __syncthreads();
    const int bcol0 = b*1024 + chunk*32;
    for (int q = t; q < 1536; q += 256) {
      const int mm = q >> 9, rem = q & 511;
      const int r = rem >> 3, c4 = (rem & 7) * 4;
      const float4 v = *reinterpret_cast<const float4*>(
          &ws[YOFF + (size_t)(mm*64 + r)*NCOL + bcol0 + c4]);
      float v0, v1, v2, v3;
      if (mm < 2) {
        const float sc = sm.cpart.sc[mm*64 + r], sf = sm.cpart.sf[mm*64 + r];
        v0 = fmaxf(sc*v.x+sf, 0.f); v1 = fmaxf(sc*v.y+sf, 0.f);
        v2 = fmaxf(sc*v.z+sf, 0.f); v3 = fmaxf(sc*v.w+sf, 0.f);
      } else { v0=v.x; v1=v.y; v2=v.z; v3=v.w; }
      const u16 h0=f2bf(v0), h1=f2bf(v1), h2=f2bf(v2), h3=f2bf(v3);
      uint2 ph; ph.x=(unsigned)h0|((unsigned)h1<<16); ph.y=(unsigned)h2|((unsigned)h3<<16);
      uint2 pl;
      pl.x=(unsigned)f2bf(v0-bf2f(h0)) | ((unsigned)f2bf(v1-bf2f(h1))<<16);
      pl.y=(unsigned)f2bf(v2-bf2f(h2)) | ((unsigned)f2bf(v3-bf2f(h3))<<16);
      *reinterpret_cast<uint2*>(&sm.cpart.Sh[mm][r][c4]) = ph;
      *reinterpret_cast<uint2*>(&sm.cpart.Sl[mm][r][c4]) = pl;
    }
    __syncthreads();
    {
      const int lane = t & 63, wid = t >> 6;
      const int lm = lane & 15, lk = lane >> 4;
      const int mt0 = (wid >> 1)*2, nt0 = (wid & 1)*2;
      const int ko = lk*8;
      short8 ah[3][2], al[3][2];
      #pragma unroll
      for (int m = 0; m < 3; ++m)
        #pragma unroll
        for (int mi = 0; mi < 2; ++mi) {
          const int row = (mt0+mi)*16 + lm;
          ah[m][mi] = *reinterpret_cast<const short8*>(&sm.cpart.Sh[m][row][ko]);
          al[m][mi] = *reinterpret_cast<const short8*>(&sm.cpart.Sl[m][row][ko]);
        }
      short8 bhf[2][2], blf[2][2];
      #pragma unroll
      for (int m = 0; m < 2; ++m)
        #pragma unroll
        for (int ni = 0; ni < 2; ++ni) {
          const int row = (nt0+ni)*16 + lm;
          bhf[m][ni] = *reinterpret_cast<const short8*>(&sm.cpart.Sh[m][row][ko]);
          blf[m][ni] = *reinterpret_cast<const short8*>(&sm.cpart.Sl[m][row][ko]);
        }
      f32x4 acc2[3][2][2];
      #pragma unroll
      for (int p=0;p<3;++p) for (int i=0;i<2;++i) for (int j=0;j<2;++j) acc2[p][i][j]=(f32x4)0.f;
      #pragma unroll
      for (int p = 0; p < 3; ++p) {
        const int am = p;
        const int bm = (p==0) ? 0 : 1;
        #pragma unroll
        for (int mi = 0; mi < 2; ++mi)
          #pragma unroll
          for (int ni = 0; ni < 2; ++ni) {
            acc2[p][mi][ni] = MFMA_B16(ah[am][mi], bhf[bm][ni], acc2[p][mi][ni]);
            acc2[p][mi][ni] = MFMA_B16(al[am][mi], bhf[bm][ni], acc2[p][mi][ni]);
            acc2[p][mi][ni] = MFMA_B16(ah[am][mi], blf[bm][ni], acc2[p][mi][ni]);
          }
      }
      float* cp = ws + CP2OFF;
      #pragma unroll
      for (int p = 0; p < 3; ++p) {
        float* base = cp + ((size_t)((b*3+p)*NCHUNK + chunk))*4096;
        #pragma unroll
        for (int mi = 0; mi < 2; ++mi)
          #pragma unroll
          for (int ni = 0; ni < 2; ++ni) {
            const int col = (nt0+ni)*16 + lm;
            #pragma unroll
            for (int r = 0; r < 4; ++r) {
              const int row = (mt0+mi)*16 + lk*4 + r;
              base[(size_t)row*64 + col] = acc2[p][mi][ni][r];
            }
          }
      }
    }
  }
  gbar(ctr, 3);

  /* ---------- P4: chunk reduction -> CM[24][4096] ---------- */
  {
    const float* cp2 = ws + CP2OFF;
    float* cm = ws + CMOFF;
    for (unsigned idx = (unsigned)bid*256 + t; idx < 24u*4096u; idx += 65536u) {
      const unsigned m = idx >> 12, e = idx & 4095u;
      const float* s = cp2 + (size_t)m*NCHUNK*4096 + e;
      float a = 0.f;
      #pragma unroll
      for (int ch = 0; ch < NCHUNK; ++ch) a += s[(size_t)ch*4096];
      cm[(size_t)m*4096 + e] = a;
    }
  }
  gbar(ctr, 4);

  /* ---------- P5: power iteration -> 1/sigma (8 blocks, 1 wave compute) ---------- */
  if (bid < 8) {
    const int b = bid;
    const int lane = t;   /* only t<64 computes */
    const float* Cf = ws + CMOFF + (size_t)(b*3+0)*4096;
    const float* Cg = ws + CMOFF + (size_t)(b*3+1)*4096;
    float cfr[64], cgr[64];
    if (t < 64) {
      #pragma unroll
      for (int k4 = 0; k4 < 16; ++k4) {
        const float4 fa = *reinterpret_cast<const float4*>(&Cf[lane*64 + k4*4]);
        const float4 fc = *reinterpret_cast<const float4*>(&Cg[lane*64 + k4*4]);
        cfr[k4*4+0]=fa.x; cfr[k4*4+1]=fa.y; cfr[k4*4+2]=fa.z; cfr[k4*4+3]=fa.w;
        cgr[k4*4+0]=fc.x; cgr[k4*4+1]=fc.y; cgr[k4*4+2]=fc.z; cgr[k4*4+3]=fc.w;
      }
    }
    float vloc = 0.125f;
    if (t < 64) sm.sigma.v[lane] = vloc;
    __syncthreads();
    const int NIT = 14;
    float lambda = 0.f;
    for (int it = 0; it <= NIT; ++it) {
      float w = 0.f;
      if (t < 64) {
        float u0=0.f,u1=0.f,u2=0.f,u3=0.f;
        #pragma unroll
        for (int j4 = 0; j4 < 16; ++j4) {
          const float4 vq = *reinterpret_cast<const float4*>(&sm.sigma.v[j4*4]);
          u0 += cfr[j4*4+0]*vq.x; u1 += cfr[j4*4+1]*vq.y;
          u2 += cfr[j4*4+2]*vq.z; u3 += cfr[j4*4+3]*vq.w;
        }
        sm.sigma.u[lane] = (u0+u1)+(u2+u3);
      }
      __syncthreads();
      if (t < 64) {
        float w0=0.f,w1=0.f,w2=0.f,w3=0.f;
        #pragma unroll
        for (int j4 = 0; j4 < 16; ++j4) {
          const float4 uq = *reinterpret_cast<const float4*>(&sm.sigma.u[j4*4]);
          w0 += cgr[j4*4+0]*uq.x; w1 += cgr[j4*4+1]*uq.y;
          w2 += cgr[j4*4+2]*uq.z; w3 += cgr[j4*4+3]*uq.w;
        }
        w = (w0+w1)+(w2+w3);
      }
      if (it == NIT) {
        if (t < 64) {
          float num = vloc * w;
          #pragma unroll
          for (int off = 32; off > 0; off >>= 1) num += __shfl_xor(num, off);
          lambda = num;
        }
      } else {
        if (t < 64) {
          float n2 = w*w;
          #pragma unroll
          for (int off = 32; off > 0; off >>= 1) n2 += __shfl_xor(n2, off);
          const float rn = rsqrtf(fmaxf(n2, 1e-30f));
          vloc = w * rn;
        }
        __syncthreads();
        if (t < 64) sm.sigma.v[lane] = vloc;
        __syncthreads();
      }
    }
    if (t == 0) ws[ISOFF + b] = rsqrtf(fmaxf(lambda, 1e-30f));
  }
  gbar(ctr, 5);

  /* ---------- P6: U = (Wv @ T) * isig, 16-row tile per block ---------- */
  {
    const int b = bid >> 5, rt = bid & 31;
    const float* T = ws + CMOFF + (size_t)(b*3+2)*4096;
    for (int q = t; q < 1024; q += 256)
      *(reinterpret_cast<float4*>(&sm.ufold.Tl[0][0]) + q) = *(reinterpret_cast<const float4*>(T) + q);
    __syncthreads();
    const float isig = ws[ISOFF + b];
    const int row = rt*16 + (t >> 4), col0 = (t & 15)*4;
    float ax=0.f, ay=0.f, az=0.f, aw=0.f;
    #pragma unroll
    for (int c = 0; c < 64; ++c) {
      const float wv = Wv[(size_t)row*64 + c];
      const float4 tv = *reinterpret_cast<const float4*>(&sm.ufold.Tl[c][col0]);
      ax += wv*tv.x; ay += wv*tv.y; az += wv*tv.z; aw += wv*tv.w;
    }
    float4 o; o.x = ax*isig; o.y = ay*isig; o.z = az*isig; o.w = aw*isig;
    *reinterpret_cast<float4*>(&ws[UOFF + ((size_t)b*512 + row)*64 + col0]) = o;
  }
  gbar(ctr, 6);

  /* ---------- P7: out = U @ F + bv + x, 4 col-tiles per block ---------- */
  {
    const int b = bid >> 5, ot = (bid >> 2) & 7, ntg = bid & 3;
    if (t < 64) {
      const float* sp = ws + SPOFF;
      const float s  = sp[t*4+0] + sp[t*4+2];
      const float s2 = sp[t*4+1] + sp[t*4+3];
      const float mean = s*(1.0f/NCOL);
      const float var  = s2*(1.0f/NCOL) - mean*mean;
      const float sc = gamma_f[t] * rsqrtf(var + EPS);
      sm.fin.scF[t] = sc; sm.fin.sfF[t] = beta_f[t] - mean*sc;
    }
    for (int q = t; q < 1024; q += 256) {
      const int row = q >> 4, k4 = (q & 15)*4;
      const float4 uv = *reinterpret_cast<const float4*>(
          &ws[UOFF + ((size_t)b*512 + ot*64 + row)*64 + k4]);
      sm.fin.Ut[k4+0][row]=uv.x; sm.fin.Ut[k4+1][row]=uv.y;
      sm.fin.Ut[k4+2][row]=uv.z; sm.fin.Ut[k4+3][row]=uv.w;
    }
    const int ti = t >> 4, tj = t & 15;
    for (int nt = 0; nt < 4; ++nt) {
      __syncthreads();
      const int ncol = ntg*4 + nt;
      for (int q = t; q < 1024; q += 256) {
        const int k = q >> 4, c4 = (q & 15)*4;
        const float4 yv = *reinterpret_cast<const float4*>(
            &ws[YOFF + (size_t)k*NCOL + b*1024 + ncol*64 + c4]);
        const float s = sm.fin.scF[k], f = sm.fin.sfF[k];
        sm.fin.Fl[k][c4+0]=fmaxf(s*yv.x+f,0.f); sm.fin.Fl[k][c4+1]=fmaxf(s*yv.y+f,0.f);
        sm.fin.Fl[k][c4+2]=fmaxf(s*yv.z+f,0.f); sm.fin.Fl[k][c4+3]=fmaxf(s*yv.w+f,0.f);
      }
      __syncthreads();
      float acc[4][4] = {};
      #pragma unroll
      for (int k = 0; k < 64; ++k) {
        const float4 a  = *reinterpret_cast<const float4*>(&sm.fin.Ut[k][ti*4]);
        const float4 bb = *reinterpret_cast<const float4*>(&sm.fin.Fl[k][tj*4]);
        FMA16(a, bb)
      }
      #pragma unroll
      for (int i = 0; i < 4; ++i) {
        const int oc = ot*64 + ti*4 + i;
        const float bvv = bv[oc];
        const size_t base = ((size_t)b*C_ + oc)*HW_ + ncol*64 + tj*4;
        const float4 xv = *reinterpret_cast<const float4*>(&x[base]);
        float4 o;
        o.x = acc[i][0]+bvv+xv.x; o.y = acc[i][1]+bvv+xv.y;
        o.z = acc[i][2]+bvv+xv.z; o.w = acc[i][3]+bvv+xv.w;
        *reinterpret_cast<float4*>(&out[base]) = o;
      }
    }
  }
}

extern "C" void kernel_launch(void* const* d_in, const int* in_sizes, int n_in,
                              void* d_out, int out_size, void* d_ws, size_t ws_size,
                              hipStream_t stream) {
  (void)in_sizes; (void)n_in; (void)out_size; (void)ws_size;
  const float* x       = (const float*)d_in[0];
  const float* Wf      = (const float*)d_in[1];
  const float* bf      = (const float*)d_in[2];
  const float* gamma_f = (const float*)d_in[3];
  const float* beta_f  = (const float*)d_in[4];
  const float* Wg      = (const float*)d_in[5];
  const float* bg      = (const float*)d_in[6];
  const float* gamma_g = (const float*)d_in[7];
  const float* beta_g  = (const float*)d_in[8];
  const float* Wh      = (const float*)d_in[9];
  const float* bh      = (const float*)d_in[10];
  const float* Wv      = (const float*)d_in[11];
  const float* bv      = (const float*)d_in[12];
  float* out = (float*)d_out;
  float* ws  = (float*)d_ws;

  k_init<<<1, 64, 0, stream>>>(ws);
  k_mega<<<NBLK, 256, 0, stream>>>(x, Wf, bf, gamma_f, beta_f,
                                   Wg, bg, gamma_g, beta_g,
                                   Wh, bh, Wv, bv, out, ws);
}

// Round 7
// 139.388 us; speedup vs baseline: 1.8080x; 1.8080x over previous
//
#include <hip/hip_runtime.h>

#define B_   8
#define C_   512
#define HW_  1024
#define NCOL (B_*HW_)   /* 8192 */
#define NROWS 192
#define EPS  1e-5f
#define NCHUNK 32

/* ws layout (float offsets) */
#define YOFF   0
#define YSZ    (NROWS*NCOL)            /* 1,572,864 */
#define SPOFF  (YOFF+YSZ)              /* stats sums [128][2] */
#define SPSZ   256
#define WOFF   (SPOFF+SPSZ)            /* W hi/lo u16: 98,304 floats */
#define WSZ    98304
#define CPOFF  (WOFF+WSZ)              /* partials [8][3][32][4096] */
#define CPSZ   (24*NCHUNK*4096)
#define CMOFF  (CPOFF+CPSZ)            /* reduced [24][4096] */
#define CMSZ   (24*4096)
#define ISOFF  (CMOFF+CMSZ)            /* inv sigma [8] pad 16 */
#define UOFF   (ISOFF+16)              /* U_raw [8][512][64] */

typedef unsigned short u16;
typedef __attribute__((ext_vector_type(8))) short short8;
typedef __attribute__((ext_vector_type(4))) float f32x4;

__device__ __forceinline__ u16 f2bf(float f) {
  unsigned u = __float_as_uint(f);
  unsigned r = u + 0x7fffu + ((u >> 16) & 1u);
  return (u16)(r >> 16);
}
__device__ __forceinline__ float bf2f(u16 h) {
  return __uint_as_float(((unsigned)h) << 16);
}
#define MFMA_B16(a,b,c) __builtin_amdgcn_mfma_f32_16x16x32_bf16(a,b,c,0,0,0)

#define FMA16(a, bb) \
  acc[0][0]+=a.x*bb.x; acc[0][1]+=a.x*bb.y; acc[0][2]+=a.x*bb.z; acc[0][3]+=a.x*bb.w; \
  acc[1][0]+=a.y*bb.x; acc[1][1]+=a.y*bb.y; acc[1][2]+=a.y*bb.z; acc[1][3]+=a.y*bb.w; \
  acc[2][0]+=a.z*bb.x; acc[2][1]+=a.z*bb.y; acc[2][2]+=a.z*bb.z; acc[2][3]+=a.z*bb.w; \
  acc[3][0]+=a.w*bb.x; acc[3][1]+=a.w*bb.y; acc[3][2]+=a.w*bb.z; acc[3][3]+=a.w*bb.w;

/* ---- P-kernel 1: split W to bf16 hi/lo; block 0 zeroes stats accumulators ---- */
__global__ __launch_bounds__(256) void k_prep(
    const float* __restrict__ Wf, const float* __restrict__ Wg,
    const float* __restrict__ Wh, float* __restrict__ ws)
{
  if (blockIdx.x == 0) ws[SPOFF + threadIdx.x] = 0.f;
  u16* Whi = (u16*)(ws + WOFF);
  u16* Wlo = Whi + NROWS*C_;
  const int e4 = blockIdx.x*256 + threadIdx.x;   /* 0..24575 */
  const int e  = e4*4;
  const int row = e >> 9, k = e & 511;
  const float* src = (row < 64) ? &Wf[row*C_ + k]
                   : (row < 128) ? &Wg[(row-64)*C_ + k]
                   : &Wh[(row-128)*C_ + k];
  const float4 v = *reinterpret_cast<const float4*>(src);
  u16 h0=f2bf(v.x), h1=f2bf(v.y), h2=f2bf(v.z), h3=f2bf(v.w);
  u16 l0=f2bf(v.x-bf2f(h0)), l1=f2bf(v.y-bf2f(h1)), l2=f2bf(v.z-bf2f(h2)), l3=f2bf(v.w-bf2f(h3));
  uint2 ph; ph.x = (unsigned)h0 | ((unsigned)h1<<16); ph.y = (unsigned)h2 | ((unsigned)h3<<16);
  uint2 pl; pl.x = (unsigned)l0 | ((unsigned)l1<<16); pl.y = (unsigned)l2 | ((unsigned)l3<<16);
  *reinterpret_cast<uint2*>(&Whi[e]) = ph;
  *reinterpret_cast<uint2*>(&Wlo[e]) = pl;
}

/* ---- Y = W @ X + bias (MFMA bf16x3) + fused BN stats atomics ---- */
__global__ __launch_bounds__(256) void k_conv(
    const float* __restrict__ x,
    const float* __restrict__ bf, const float* __restrict__ bg, const float* __restrict__ bh,
    float* __restrict__ ws)
{
  __shared__ u16 Xh[8*32*8];
  __shared__ u16 Xl[8*32*8];
  const u16* Whi = (const u16*)(ws + WOFF);
  const u16* Wlo = Whi + NROWS*C_;
  const int n0  = blockIdx.x * 32;
  const int b   = n0 >> 10;
  const int hw0 = n0 & 1023;
  const int t   = threadIdx.x;
  const int lane = t & 63;
  const int wid  = t >> 6;
  const int wrow0 = wid * 48;
  const int cst = t & 31, kg2 = t >> 5;
  const int lm = lane & 15, lk = lane >> 4;

  f32x4 acc[3][2];
  #pragma unroll
  for (int i=0;i<3;++i) { acc[i][0]=(f32x4)0.f; acc[i][1]=(f32x4)0.f; }

  for (int kk = 0; kk < C_; kk += 64) {
    __syncthreads();
    {
      const float* xp = x + ((size_t)(b*C_ + kk + kg2*8))*HW_ + hw0 + cst;
      u16 hb[8], lb[8];
      #pragma unroll
      for (int i=0;i<8;++i) {
        const float v = xp[(size_t)i*HW_];
        hb[i] = f2bf(v); lb[i] = f2bf(v - bf2f(hb[i]));
      }
      uint4 ph, pl;
      ph.x=(unsigned)hb[0]|((unsigned)hb[1]<<16); ph.y=(unsigned)hb[2]|((unsigned)hb[3]<<16);
      ph.z=(unsigned)hb[4]|((unsigned)hb[5]<<16); ph.w=(unsigned)hb[6]|((unsigned)hb[7]<<16);
      pl.x=(unsigned)lb[0]|((unsigned)lb[1]<<16); pl.y=(unsigned)lb[2]|((unsigned)lb[3]<<16);
      pl.z=(unsigned)lb[4]|((unsigned)lb[5]<<16); pl.w=(unsigned)lb[6]|((unsigned)lb[7]<<16);
      *reinterpret_cast<uint4*>(&Xh[(kg2*32+cst)*8]) = ph;
      *reinterpret_cast<uint4*>(&Xl[(kg2*32+cst)*8]) = pl;
    }
    __syncthreads();
    #pragma unroll
    for (int kb = 0; kb < 2; ++kb) {
      short8 bhf[2], blf[2];
      #pragma unroll
      for (int nt = 0; nt < 2; ++nt) {
        const int col = nt*16 + lm;
        const int idx = ((kb*4 + lk)*32 + col)*8;
        bhf[nt] = *reinterpret_cast<const short8*>(&Xh[idx]);
        blf[nt] = *reinterpret_cast<const short8*>(&Xl[idx]);
      }
      #pragma unroll
      for (int mt = 0; mt < 3; ++mt) {
        const int row = wrow0 + mt*16 + lm;
        const size_t widx = (size_t)row*C_ + kk + kb*32 + lk*8;
        const short8 ah = *reinterpret_cast<const short8*>(&Whi[widx]);
        const short8 al = *reinterpret_cast<const short8*>(&Wlo[widx]);
        #pragma unroll
        for (int nt = 0; nt < 2; ++nt) {
          acc[mt][nt] = MFMA_B16(ah, bhf[nt], acc[mt][nt]);
          acc[mt][nt] = MFMA_B16(al, bhf[nt], acc[mt][nt]);
          acc[mt][nt] = MFMA_B16(ah, blf[nt], acc[mt][nt]);
        }
      }
    }
  }
  /* epilogue: bias, Y store, fused stats (rows<128) */
  #pragma unroll
  for (int mt = 0; mt < 3; ++mt) {
    const int rbase = wrow0 + mt*16;
    const float* bp = (rbase < 64) ? bf : (rbase < 128) ? bg : bh;
    const int rloc0 = (rbase & 63) + lk*4;
    #pragma unroll
    for (int r = 0; r < 4; ++r) {
      const int row = rbase + lk*4 + r;
      const float bi = bp[rloc0 + r];
      const float y0 = acc[mt][0][r] + bi;
      const float y1 = acc[mt][1][r] + bi;
      ws[YOFF + (size_t)row*NCOL + n0 + lm]      = y0;
      ws[YOFF + (size_t)row*NCOL + n0 + 16 + lm] = y1;
      if (rbase < 128) {           /* wave-uniform */
        float s  = y0 + y1;
        float s2 = y0*y0 + y1*y1;
        #pragma unroll
        for (int off = 1; off < 16; off <<= 1) {
          s  += __shfl_xor(s,  off);
          s2 += __shfl_xor(s2, off);
        }
        if (lm == 0) {
          atomicAdd(&ws[SPOFF + row*2 + 0], s);
          atomicAdd(&ws[SPOFF + row*2 + 1], s2);
        }
      }
    }
  }
}

/* ---- fused Cf/Cg/T partials via MFMA bf16x3, 32-col chunk per block ---- */
__global__ __launch_bounds__(256) void k_cpart(
    const float* __restrict__ gamma_f, const float* __restrict__ beta_f,
    const float* __restrict__ gamma_g, const float* __restrict__ beta_g,
    float* __restrict__ ws)
{
  __shared__ u16 Sh[3][64][40];
  __shared__ u16 Sl[3][64][40];
  __shared__ float scs[128], sfs[128];
  const int chunk = blockIdx.x, b = blockIdx.y;
  const int t = threadIdx.x;
  if (t < 128) {
    const float s  = ws[SPOFF + t*2 + 0];
    const float s2 = ws[SPOFF + t*2 + 1];
    const float mean = s*(1.0f/NCOL);
    const float var  = s2*(1.0f/NCOL) - mean*mean;
    const float g  = (t < 64) ? gamma_f[t] : gamma_g[t-64];
    const float be = (t < 64) ? beta_f[t]  : beta_g[t-64];
    const float sc = g * rsqrtf(var + EPS);
    scs[t] = sc; sfs[t] = be - mean*sc;
  }
  __syncthreads();
  const int bcol0 = b*1024 + chunk*32;
  for (int q = t; q < 1536; q += 256) {
    const int mm = q >> 9, rem = q & 511;
    const int r = rem >> 3, c4 = (rem & 7) * 4;
    const float4 v = *reinterpret_cast<const float4*>(
        &ws[YOFF + (size_t)(mm*64 + r)*NCOL + bcol0 + c4]);
    float v0, v1, v2, v3;
    if (mm < 2) {
      const float sc = scs[mm*64 + r], sf = sfs[mm*64 + r];
      v0 = fmaxf(sc*v.x+sf, 0.f); v1 = fmaxf(sc*v.y+sf, 0.f);
      v2 = fmaxf(sc*v.z+sf, 0.f); v3 = fmaxf(sc*v.w+sf, 0.f);
    } else { v0=v.x; v1=v.y; v2=v.z; v3=v.w; }
    const u16 h0=f2bf(v0), h1=f2bf(v1), h2=f2bf(v2), h3=f2bf(v3);
    uint2 ph; ph.x=(unsigned)h0|((unsigned)h1<<16); ph.y=(unsigned)h2|((unsigned)h3<<16);
    uint2 pl;
    pl.x=(unsigned)f2bf(v0-bf2f(h0)) | ((unsigned)f2bf(v1-bf2f(h1))<<16);
    pl.y=(unsigned)f2bf(v2-bf2f(h2)) | ((unsigned)f2bf(v3-bf2f(h3))<<16);
    *reinterpret_cast<uint2*>(&Sh[mm][r][c4]) = ph;
    *reinterpret_cast<uint2*>(&Sl[mm][r][c4]) = pl;
  }
  __syncthreads();
  {
    const int lane = t & 63, wid = t >> 6;
    const int lm = lane & 15, lk = lane >> 4;
    const int mt0 = (wid >> 1)*2, nt0 = (wid & 1)*2;
    const int ko = lk*8;
    short8 ah[3][2], al[3][2];
    #pragma unroll
    for (int m = 0; m < 3; ++m)
      #pragma unroll
      for (int mi = 0; mi < 2; ++mi) {
        const int row = (mt0+mi)*16 + lm;
        ah[m][mi] = *reinterpret_cast<const short8*>(&Sh[m][row][ko]);
        al[m][mi] = *reinterpret_cast<const short8*>(&Sl[m][row][ko]);
      }
    short8 bhf[2][2], blf[2][2];
    #pragma unroll
    for (int m = 0; m < 2; ++m)
      #pragma unroll
      for (int ni = 0; ni < 2; ++ni) {
        const int row = (nt0+ni)*16 + lm;
        bhf[m][ni] = *reinterpret_cast<const short8*>(&Sh[m][row][ko]);
        blf[m][ni] = *reinterpret_cast<const short8*>(&Sl[m][row][ko]);
      }
    f32x4 acc2[3][2][2];
    #pragma unroll
    for (int p=0;p<3;++p) for (int i=0;i<2;++i) for (int j=0;j<2;++j) acc2[p][i][j]=(f32x4)0.f;
    #pragma unroll
    for (int p = 0; p < 3; ++p) {
      const int am = p;
      const int bm = (p==0) ? 0 : 1;
      #pragma unroll
      for (int mi = 0; mi < 2; ++mi)
        #pragma unroll
        for (int ni = 0; ni < 2; ++ni) {
          acc2[p][mi][ni] = MFMA_B16(ah[am][mi], bhf[bm][ni], acc2[p][mi][ni]);
          acc2[p][mi][ni] = MFMA_B16(al[am][mi], bhf[bm][ni], acc2[p][mi][ni]);
          acc2[p][mi][ni] = MFMA_B16(ah[am][mi], blf[bm][ni], acc2[p][mi][ni]);
        }
    }
    float* cp = ws + CPOFF;
    #pragma unroll
    for (int p = 0; p < 3; ++p) {
      float* base = cp + ((size_t)((b*3+p)*NCHUNK + chunk))*4096;
      #pragma unroll
      for (int mi = 0; mi < 2; ++mi)
        #pragma unroll
        for (int ni = 0; ni < 2; ++ni) {
          const int col = (nt0+ni)*16 + lm;
          #pragma unroll
          for (int r = 0; r < 4; ++r) {
            const int row = (mt0+mi)*16 + lk*4 + r;
            base[(size_t)row*64 + col] = acc2[p][mi][ni][r];
          }
        }
    }
  }
}

/* ---- coalesced chunk reduction: partials -> CM[24][4096] ---- */
__global__ __launch_bounds__(256) void k_creduce(float* __restrict__ ws)
{
  const int m = blockIdx.y;                    /* b*3+p */
  const int q = blockIdx.x*256 + threadIdx.x;  /* 0..1023 float4 index */
  const float4* src = reinterpret_cast<const float4*>(ws + CPOFF) + (size_t)m*NCHUNK*1024;
  float4 s = {0.f,0.f,0.f,0.f};
  #pragma unroll 8
  for (int ch = 0; ch < NCHUNK; ++ch) {
    const float4 p = src[(size_t)ch*1024 + q];
    s.x+=p.x; s.y+=p.y; s.z+=p.z; s.w+=p.w;
  }
  *(reinterpret_cast<float4*>(ws + CMOFF) + (size_t)m*1024 + q) = s;
}

/* ---- merged: bid<64 -> U_raw = Wv @ T  |  bid>=64 -> power iteration 1/sigma ---- */
__global__ __launch_bounds__(256) void k_su(const float* __restrict__ Wv, float* __restrict__ ws)
{
  __shared__ float smA[64][64];
  __shared__ float smB[64][64];
  const int bid = blockIdx.x;
  const int t = threadIdx.x;
  if (bid < 64) {
    /* ufold: b = bid>>3, rt = bid&7, 64-row tile of U_raw */
    const int b = bid >> 3, rt = bid & 7;
    const float* T = ws + CMOFF + (size_t)(b*3+2)*4096;
    for (int q = t; q < 1024; q += 256)
      *(reinterpret_cast<float4*>(&smB[0][0]) + q) = *(reinterpret_cast<const float4*>(T) + q);
    for (int q = t; q < 1024; q += 256) {
      const int row = q >> 4;
      const int c4  = (q & 15) * 4;
      const float4 wv = *reinterpret_cast<const float4*>(&Wv[(size_t)(rt*64+row)*64 + c4]);
      smA[c4+0][row]=wv.x; smA[c4+1][row]=wv.y; smA[c4+2][row]=wv.z; smA[c4+3][row]=wv.w;
    }
    __syncthreads();
    const int ti = t >> 4, tj = t & 15;
    float acc[4][4] = {};
    #pragma unroll
    for (int c = 0; c < 64; ++c) {
      const float4 a  = *reinterpret_cast<const float4*>(&smA[c][ti*4]);
      const float4 bb = *reinterpret_cast<const float4*>(&smB[c][tj*4]);
      FMA16(a, bb)
    }
    #pragma unroll
    for (int i = 0; i < 4; ++i) {
      float4 o; o.x = acc[i][0]; o.y = acc[i][1]; o.z = acc[i][2]; o.w = acc[i][3];
      *reinterpret_cast<float4*>(&ws[UOFF + ((size_t)b*512 + rt*64 + ti*4+i)*64 + tj*4]) = o;
    }
  } else {
    /* sigma: b = bid-64 */
    const int b = bid - 64;
    float* vsh = &smA[0][0];
    float* ush = &smA[1][0];
    const float* Cf = ws + CMOFF + (size_t)(b*3+0)*4096;
    const float* Cg = ws + CMOFF + (size_t)(b*3+1)*4096;
    float cfr[64], cgr[64];
    if (t < 64) {
      #pragma unroll
      for (int k4 = 0; k4 < 16; ++k4) {
        const float4 fa = *reinterpret_cast<const float4*>(&Cf[t*64 + k4*4]);
        const float4 fc = *reinterpret_cast<const float4*>(&Cg[t*64 + k4*4]);
        cfr[k4*4+0]=fa.x; cfr[k4*4+1]=fa.y; cfr[k4*4+2]=fa.z; cfr[k4*4+3]=fa.w;
        cgr[k4*4+0]=fc.x; cgr[k4*4+1]=fc.y; cgr[k4*4+2]=fc.z; cgr[k4*4+3]=fc.w;
      }
    }
    float vloc = 0.125f;
    if (t < 64) vsh[t] = vloc;
    __syncthreads();
    const int NIT = 16;
    float lambda = 0.f;
    for (int it = 0; it <= NIT; ++it) {
      if (t < 64) {
        float u0=0.f,u1=0.f,u2=0.f,u3=0.f;
        #pragma unroll
        for (int j4 = 0; j4 < 16; ++j4) {
          const float4 vq = *reinterpret_cast<const float4*>(&vsh[j4*4]);
          u0 += cfr[j4*4+0]*vq.x; u1 += cfr[j4*4+1]*vq.y;
          u2 += cfr[j4*4+2]*vq.z; u3 += cfr[j4*4+3]*vq.w;
        }
        ush[t] = (u0+u1)+(u2+u3);
      }
      __syncthreads();
      float w = 0.f;
      if (t < 64) {
        float w0=0.f,w1=0.f,w2=0.f,w3=0.f;
        #pragma unroll
        for (int j4 = 0; j4 < 16; ++j4) {
          const float4 uq = *reinterpret_cast<const float4*>(&ush[j4*4]);
          w0 += cgr[j4*4+0]*uq.x; w1 += cgr[j4*4+1]*uq.y;
          w2 += cgr[j4*4+2]*uq.z; w3 += cgr[j4*4+3]*uq.w;
        }
        w = (w0+w1)+(w2+w3);
      }
      if (it == NIT) {
        if (t < 64) {
          float num = vloc * w;
          #pragma unroll
          for (int off = 32; off > 0; off >>= 1) num += __shfl_xor(num, off);
          lambda = num;
        }
      } else {
        if (t < 64) {
          float n2 = w*w;
          #pragma unroll
          for (int off = 32; off > 0; off >>= 1) n2 += __shfl_xor(n2, off);
          const float rn = rsqrtf(fmaxf(n2, 1e-30f));
          vloc = w * rn;
        }
        __syncthreads();
        if (t < 64) vsh[t] = vloc;
        __syncthreads();
      }
    }
    if (t == 0) ws[ISOFF + b] = rsqrtf(fmaxf(lambda, 1e-30f));
  }
}

/* ---- out = isig*(U_raw @ F) + bv + x ---- */
__global__ __launch_bounds__(256) void k_final(
    const float* __restrict__ x, const float* __restrict__ bv,
    const float* __restrict__ gamma_f, const float* __restrict__ beta_f,
    float* __restrict__ out, const float* __restrict__ ws)
{
  __shared__ float Ut[64][64];
  __shared__ float Fl[64][64];
  __shared__ float scF[64], sfF[64];
  const int nt = blockIdx.x, ot = blockIdx.y, b = blockIdx.z;
  const int t = threadIdx.x;
  if (t < 64) {
    const float s  = ws[SPOFF + t*2 + 0];
    const float s2 = ws[SPOFF + t*2 + 1];
    const float mean = s*(1.0f/NCOL);
    const float var  = s2*(1.0f/NCOL) - mean*mean;
    const float sc = gamma_f[t] * rsqrtf(var + EPS);
    scF[t] = sc; sfF[t] = beta_f[t] - mean*sc;
  }
  for (int q = t; q < 1024; q += 256) {
    const int row = q >> 4, k4 = (q & 15)*4;
    const float4 uv = *reinterpret_cast<const float4*>(
        &ws[UOFF + ((size_t)b*512 + ot*64 + row)*64 + k4]);
    Ut[k4+0][row]=uv.x; Ut[k4+1][row]=uv.y; Ut[k4+2][row]=uv.z; Ut[k4+3][row]=uv.w;
  }
  for (int q = t; q < 1024; q += 256) {
    const int k = q >> 4, c4 = (q & 15)*4;
    const float4 yv = *reinterpret_cast<const float4*>(
        &ws[YOFF + (size_t)k*NCOL + b*1024 + nt*64 + c4]);
    /* scF/sfF written this iteration; need them visible: they were written by t<64 before
       any read below — enforce with barrier before use */
    Fl[k][c4+0]=yv.x; Fl[k][c4+1]=yv.y; Fl[k][c4+2]=yv.z; Fl[k][c4+3]=yv.w;
  }
  __syncthreads();
  /* apply BN+relu in LDS (after barrier so scF/sfF valid) */
  for (int q = t; q < 1024; q += 256) {
    const int k = q >> 4, c4 = (q & 15)*4;
    const float s = scF[k], f = sfF[k];
    Fl[k][c4+0]=fmaxf(s*Fl[k][c4+0]+f,0.f); Fl[k][c4+1]=fmaxf(s*Fl[k][c4+1]+f,0.f);
    Fl[k][c4+2]=fmaxf(s*Fl[k][c4+2]+f,0.f); Fl[k][c4+3]=fmaxf(s*Fl[k][c4+3]+f,0.f);
  }
  __syncthreads();
  const float isig = ws[ISOFF + b];
  const int ti = t >> 4, tj = t & 15;
  float acc[4][4] = {};
  #pragma unroll
  for (int k = 0; k < 64; ++k) {
    const float4 a  = *reinterpret_cast<const float4*>(&Ut[k][ti*4]);
    const float4 bb = *reinterpret_cast<const float4*>(&Fl[k][tj*4]);
    FMA16(a, bb)
  }
  #pragma unroll
  for (int i = 0; i < 4; ++i) {
    const int oc = ot*64 + ti*4 + i;
    const float bvv = bv[oc];
    const size_t base = ((size_t)b*C_ + oc)*HW_ + nt*64 + tj*4;
    const float4 xv = *reinterpret_cast<const float4*>(&x[base]);
    float4 o;
    o.x = acc[i][0]*isig+bvv+xv.x; o.y = acc[i][1]*isig+bvv+xv.y;
    o.z = acc[i][2]*isig+bvv+xv.z; o.w = acc[i][3]*isig+bvv+xv.w;
    *reinterpret_cast<float4*>(&out[base]) = o;
  }
}

extern "C" void kernel_launch(void* const* d_in, const int* in_sizes, int n_in,
                              void* d_out, int out_size, void* d_ws, size_t ws_size,
                              hipStream_t stream) {
  (void)in_sizes; (void)n_in; (void)out_size; (void)ws_size;
  const float* x       = (const float*)d_in[0];
  const float* Wf      = (const float*)d_in[1];
  const float* bf      = (const float*)d_in[2];
  const float* gamma_f = (const float*)d_in[3];
  const float* beta_f  = (const float*)d_in[4];
  const float* Wg      = (const float*)d_in[5];
  const float* bg      = (const float*)d_in[6];
  const float* gamma_g = (const float*)d_in[7];
  const float* beta_g  = (const float*)d_in[8];
  const float* Wh      = (const float*)d_in[9];
  const float* bh      = (const float*)d_in[10];
  const float* Wv      = (const float*)d_in[11];
  const float* bv      = (const float*)d_in[12];
  float* out = (float*)d_out;
  float* ws  = (float*)d_ws;

  k_prep   <<<96,              256, 0, stream>>>(Wf, Wg, Wh, ws);
  k_conv   <<<256,             256, 0, stream>>>(x, bf, bg, bh, ws);
  k_cpart  <<<dim3(NCHUNK,8),  256, 0, stream>>>(gamma_f, beta_f, gamma_g, beta_g, ws);
  k_creduce<<<dim3(4,24),      256, 0, stream>>>(ws);
  k_su     <<<72,              256, 0, stream>>>(Wv, ws);
  k_final  <<<dim3(16,8,8),    256, 0, stream>>>(x, bv, gamma_f, beta_f, out, ws);
}

// Round 8
// 77.644 us; speedup vs baseline: 3.2457x; 1.7952x over previous
//
#include <hip/hip_runtime.h>

#define B_   8
#define C_   512
#define HW_  1024
#define NCOL (B_*HW_)   /* 8192 */
#define NROWS 192
#define EPS  1e-5f
#define NCHUNK 32

/* ws layout (float offsets) */
#define YOFF   0
#define YSZ    (NROWS*NCOL)            /* 1,572,864 */
#define SPOFF  (YOFF+YSZ)              /* stats sums [128][2] */
#define SPSZ   256
#define WOFF   (SPOFF+SPSZ)            /* W hi/lo u16: 98,304 floats */
#define WSZ    98304
#define CPOFF  (WOFF+WSZ)              /* partials [8][3][32][4096] */
#define CPSZ   (24*NCHUNK*4096)
#define CMOFF  (CPOFF+CPSZ)            /* reduced [24][4096] */
#define CMSZ   (24*4096)
#define ISOFF  (CMOFF+CMSZ)            /* inv sigma [8] pad 16 */
#define UOFF   (ISOFF+16)              /* U_raw [8][512][64] */

typedef unsigned short u16;
typedef __attribute__((ext_vector_type(8))) short short8;
typedef __attribute__((ext_vector_type(4))) float f32x4;

__device__ __forceinline__ u16 f2bf(float f) {
  unsigned u = __float_as_uint(f);
  unsigned r = u + 0x7fffu + ((u >> 16) & 1u);
  return (u16)(r >> 16);
}
__device__ __forceinline__ float bf2f(u16 h) {
  return __uint_as_float(((unsigned)h) << 16);
}
#define MFMA_B16(a,b,c) __builtin_amdgcn_mfma_f32_16x16x32_bf16(a,b,c,0,0,0)

#define FMA16(a, bb) \
  acc[0][0]+=a.x*bb.x; acc[0][1]+=a.x*bb.y; acc[0][2]+=a.x*bb.z; acc[0][3]+=a.x*bb.w; \
  acc[1][0]+=a.y*bb.x; acc[1][1]+=a.y*bb.y; acc[1][2]+=a.y*bb.z; acc[1][3]+=a.y*bb.w; \
  acc[2][0]+=a.z*bb.x; acc[2][1]+=a.z*bb.y; acc[2][2]+=a.z*bb.z; acc[2][3]+=a.z*bb.w; \
  acc[3][0]+=a.w*bb.x; acc[3][1]+=a.w*bb.y; acc[3][2]+=a.w*bb.z; acc[3][3]+=a.w*bb.w;

/* ---- split W to bf16 hi/lo ---- */
__global__ __launch_bounds__(256) void k_prep(
    const float* __restrict__ Wf, const float* __restrict__ Wg,
    const float* __restrict__ Wh, float* __restrict__ ws)
{
  u16* Whi = (u16*)(ws + WOFF);
  u16* Wlo = Whi + NROWS*C_;
  const int e4 = blockIdx.x*256 + threadIdx.x;   /* 0..24575 */
  const int e  = e4*4;
  const int row = e >> 9, k = e & 511;
  const float* src = (row < 64) ? &Wf[row*C_ + k]
                   : (row < 128) ? &Wg[(row-64)*C_ + k]
                   : &Wh[(row-128)*C_ + k];
  const float4 v = *reinterpret_cast<const float4*>(src);
  u16 h0=f2bf(v.x), h1=f2bf(v.y), h2=f2bf(v.z), h3=f2bf(v.w);
  u16 l0=f2bf(v.x-bf2f(h0)), l1=f2bf(v.y-bf2f(h1)), l2=f2bf(v.z-bf2f(h2)), l3=f2bf(v.w-bf2f(h3));
  uint2 ph; ph.x = (unsigned)h0 | ((unsigned)h1<<16); ph.y = (unsigned)h2 | ((unsigned)h3<<16);
  uint2 pl; pl.x = (unsigned)l0 | ((unsigned)l1<<16); pl.y = (unsigned)l2 | ((unsigned)l3<<16);
  *reinterpret_cast<uint2*>(&Whi[e]) = ph;
  *reinterpret_cast<uint2*>(&Wlo[e]) = pl;
}

/* ---- Y = W @ X + bias (MFMA bf16x3); all x-loads issued upfront ---- */
__global__ __launch_bounds__(256) void k_conv(
    const float* __restrict__ x,
    const float* __restrict__ bf, const float* __restrict__ bg, const float* __restrict__ bh,
    float* __restrict__ ws)
{
  __shared__ u16 Xh[8*32*8];
  __shared__ u16 Xl[8*32*8];
  const u16* Whi = (const u16*)(ws + WOFF);
  const u16* Wlo = Whi + NROWS*C_;
  const int n0  = blockIdx.x * 32;
  const int b   = n0 >> 10;
  const int hw0 = n0 & 1023;
  const int t   = threadIdx.x;
  const int lane = t & 63;
  const int wid  = t >> 6;
  const int wrow0 = wid * 48;
  const int cst = t & 31, kg2 = t >> 5;
  const int lm = lane & 15, lk = lane >> 4;

  /* issue the thread's entire x-column (64 values) upfront: one latency wait */
  float xr[64];
  {
    const float* xp = x + ((size_t)(b*C_ + kg2*8))*HW_ + hw0 + cst;
    #pragma unroll
    for (int j = 0; j < 8; ++j)
      #pragma unroll
      for (int i = 0; i < 8; ++i)
        xr[j*8+i] = xp[(size_t)(j*64 + i)*HW_];
  }

  f32x4 acc[3][2];
  #pragma unroll
  for (int i=0;i<3;++i) { acc[i][0]=(f32x4)0.f; acc[i][1]=(f32x4)0.f; }

  #pragma unroll
  for (int j = 0; j < 8; ++j) {
    const int kk = j*64;
    __syncthreads();   /* previous iter's MFMA reads done */
    {
      u16 hb[8], lb[8];
      #pragma unroll
      for (int i=0;i<8;++i) {
        const float v = xr[j*8+i];
        hb[i] = f2bf(v); lb[i] = f2bf(v - bf2f(hb[i]));
      }
      uint4 ph, pl;
      ph.x=(unsigned)hb[0]|((unsigned)hb[1]<<16); ph.y=(unsigned)hb[2]|((unsigned)hb[3]<<16);
      ph.z=(unsigned)hb[4]|((unsigned)hb[5]<<16); ph.w=(unsigned)hb[6]|((unsigned)hb[7]<<16);
      pl.x=(unsigned)lb[0]|((unsigned)lb[1]<<16); pl.y=(unsigned)lb[2]|((unsigned)lb[3]<<16);
      pl.z=(unsigned)lb[4]|((unsigned)lb[5]<<16); pl.w=(unsigned)lb[6]|((unsigned)lb[7]<<16);
      *reinterpret_cast<uint4*>(&Xh[(kg2*32+cst)*8]) = ph;
      *reinterpret_cast<uint4*>(&Xl[(kg2*32+cst)*8]) = pl;
    }
    __syncthreads();
    #pragma unroll
    for (int kb = 0; kb < 2; ++kb) {
      short8 bhf[2], blf[2];
      #pragma unroll
      for (int nt = 0; nt < 2; ++nt) {
        const int col = nt*16 + lm;
        const int idx = ((kb*4 + lk)*32 + col)*8;
        bhf[nt] = *reinterpret_cast<const short8*>(&Xh[idx]);
        blf[nt] = *reinterpret_cast<const short8*>(&Xl[idx]);
      }
      #pragma unroll
      for (int mt = 0; mt < 3; ++mt) {
        const int row = wrow0 + mt*16 + lm;
        const size_t widx = (size_t)row*C_ + kk + kb*32 + lk*8;
        const short8 ah = *reinterpret_cast<const short8*>(&Whi[widx]);
        const short8 al = *reinterpret_cast<const short8*>(&Wlo[widx]);
        #pragma unroll
        for (int nt = 0; nt < 2; ++nt) {
          acc[mt][nt] = MFMA_B16(ah, bhf[nt], acc[mt][nt]);
          acc[mt][nt] = MFMA_B16(al, bhf[nt], acc[mt][nt]);
          acc[mt][nt] = MFMA_B16(ah, blf[nt], acc[mt][nt]);
        }
      }
    }
  }
  /* epilogue: bias + Y store (no atomics) */
  #pragma unroll
  for (int mt = 0; mt < 3; ++mt) {
    const int rbase = wrow0 + mt*16;
    const float* bp = (rbase < 64) ? bf : (rbase < 128) ? bg : bh;
    const int rloc0 = (rbase & 63) + lk*4;
    #pragma unroll
    for (int nt = 0; nt < 2; ++nt) {
      const int col = n0 + nt*16 + lm;
      #pragma unroll
      for (int r = 0; r < 4; ++r) {
        const int row = rbase + lk*4 + r;
        ws[YOFF + (size_t)row*NCOL + col] = acc[mt][nt][r] + bp[rloc0 + r];
      }
    }
  }
}

/* ---- per-row sum/sumsq over 8192 cols for rows 0..127 ---- */
__global__ __launch_bounds__(256) void k_stats(float* __restrict__ ws)
{
  const int r = blockIdx.x;   /* 0..127 */
  const float4* Yr = reinterpret_cast<const float4*>(ws + YOFF + (size_t)r*NCOL);
  const int t = threadIdx.x;
  float s = 0.f, s2 = 0.f;
  for (int n = t; n < NCOL/4; n += 256) {
    const float4 v = Yr[n];
    s  += (v.x+v.y)+(v.z+v.w);
    s2 += (v.x*v.x+v.y*v.y)+(v.z*v.z+v.w*v.w);
  }
  __shared__ float sh[256], sh2[256];
  sh[t] = s; sh2[t] = s2;
  __syncthreads();
  for (int st = 128; st > 0; st >>= 1) {
    if (t < st) { sh[t] += sh[t+st]; sh2[t] += sh2[t+st]; }
    __syncthreads();
  }
  if (t == 0) {
    ws[SPOFF + r*2 + 0] = sh[0];
    ws[SPOFF + r*2 + 1] = sh2[0];
  }
}

/* ---- fused Cf/Cg/T partials via MFMA bf16x3, 32-col chunk per block ---- */
__global__ __launch_bounds__(256) void k_cpart(
    const float* __restrict__ gamma_f, const float* __restrict__ beta_f,
    const float* __restrict__ gamma_g, const float* __restrict__ beta_g,
    float* __restrict__ ws)
{
  __shared__ u16 Sh[3][64][40];
  __shared__ u16 Sl[3][64][40];
  __shared__ float scs[128], sfs[128];
  const int chunk = blockIdx.x, b = blockIdx.y;
  const int t = threadIdx.x;
  if (t < 128) {
    const float s  = ws[SPOFF + t*2 + 0];
    const float s2 = ws[SPOFF + t*2 + 1];
    const float mean = s*(1.0f/NCOL);
    const float var  = s2*(1.0f/NCOL) - mean*mean;
    const float g  = (t < 64) ? gamma_f[t] : gamma_g[t-64];
    const float be = (t < 64) ? beta_f[t]  : beta_g[t-64];
    const float sc = g * rsqrtf(var + EPS);
    scs[t] = sc; sfs[t] = be - mean*sc;
  }
  __syncthreads();
  const int bcol0 = b*1024 + chunk*32;
  for (int q = t; q < 1536; q += 256) {
    const int mm = q >> 9, rem = q & 511;
    const int r = rem >> 3, c4 = (rem & 7) * 4;
    const float4 v = *reinterpret_cast<const float4*>(
        &ws[YOFF + (size_t)(mm*64 + r)*NCOL + bcol0 + c4]);
    float v0, v1, v2, v3;
    if (mm < 2) {
      const float sc = scs[mm*64 + r], sf = sfs[mm*64 + r];
      v0 = fmaxf(sc*v.x+sf, 0.f); v1 = fmaxf(sc*v.y+sf, 0.f);
      v2 = fmaxf(sc*v.z+sf, 0.f); v3 = fmaxf(sc*v.w+sf, 0.f);
    } else { v0=v.x; v1=v.y; v2=v.z; v3=v.w; }
    const u16 h0=f2bf(v0), h1=f2bf(v1), h2=f2bf(v2), h3=f2bf(v3);
    uint2 ph; ph.x=(unsigned)h0|((unsigned)h1<<16); ph.y=(unsigned)h2|((unsigned)h3<<16);
    uint2 pl;
    pl.x=(unsigned)f2bf(v0-bf2f(h0)) | ((unsigned)f2bf(v1-bf2f(h1))<<16);
    pl.y=(unsigned)f2bf(v2-bf2f(h2)) | ((unsigned)f2bf(v3-bf2f(h3))<<16);
    *reinterpret_cast<uint2*>(&Sh[mm][r][c4]) = ph;
    *reinterpret_cast<uint2*>(&Sl[mm][r][c4]) = pl;
  }
  __syncthreads();
  {
    const int lane = t & 63, wid = t >> 6;
    const int lm = lane & 15, lk = lane >> 4;
    const int mt0 = (wid >> 1)*2, nt0 = (wid & 1)*2;
    const int ko = lk*8;
    short8 ah[3][2], al[3][2];
    #pragma unroll
    for (int m = 0; m < 3; ++m)
      #pragma unroll
      for (int mi = 0; mi < 2; ++mi) {
        const int row = (mt0+mi)*16 + lm;
        ah[m][mi] = *reinterpret_cast<const short8*>(&Sh[m][row][ko]);
        al[m][mi] = *reinterpret_cast<const short8*>(&Sl[m][row][ko]);
      }
    short8 bhf[2][2], blf[2][2];
    #pragma unroll
    for (int m = 0; m < 2; ++m)
      #pragma unroll
      for (int ni = 0; ni < 2; ++ni) {
        const int row = (nt0+ni)*16 + lm;
        bhf[m][ni] = *reinterpret_cast<const short8*>(&Sh[m][row][ko]);
        blf[m][ni] = *reinterpret_cast<const short8*>(&Sl[m][row][ko]);
      }
    f32x4 acc2[3][2][2];
    #pragma unroll
    for (int p=0;p<3;++p) for (int i=0;i<2;++i) for (int j=0;j<2;++j) acc2[p][i][j]=(f32x4)0.f;
    #pragma unroll
    for (int p = 0; p < 3; ++p) {
      const int am = p;
      const int bm = (p==0) ? 0 : 1;
      #pragma unroll
      for (int mi = 0; mi < 2; ++mi)
        #pragma unroll
        for (int ni = 0; ni < 2; ++ni) {
          acc2[p][mi][ni] = MFMA_B16(ah[am][mi], bhf[bm][ni], acc2[p][mi][ni]);
          acc2[p][mi][ni] = MFMA_B16(al[am][mi], bhf[bm][ni], acc2[p][mi][ni]);
          acc2[p][mi][ni] = MFMA_B16(ah[am][mi], blf[bm][ni], acc2[p][mi][ni]);
        }
    }
    float* cp = ws + CPOFF;
    #pragma unroll
    for (int p = 0; p < 3; ++p) {
      float* base = cp + ((size_t)((b*3+p)*NCHUNK + chunk))*4096;
      #pragma unroll
      for (int mi = 0; mi < 2; ++mi)
        #pragma unroll
        for (int ni = 0; ni < 2; ++ni) {
          const int col = (nt0+ni)*16 + lm;
          #pragma unroll
          for (int r = 0; r < 4; ++r) {
            const int row = (mt0+mi)*16 + lk*4 + r;
            base[(size_t)row*64 + col] = acc2[p][mi][ni][r];
          }
        }
    }
  }
}

/* ---- coalesced chunk reduction: partials -> CM[24][4096] ---- */
__global__ __launch_bounds__(256) void k_creduce(float* __restrict__ ws)
{
  const int m = blockIdx.y;                    /* b*3+p */
  const int q = blockIdx.x*256 + threadIdx.x;  /* 0..1023 float4 index */
  const float4* src = reinterpret_cast<const float4*>(ws + CPOFF) + (size_t)m*NCHUNK*1024;
  float4 s = {0.f,0.f,0.f,0.f};
  #pragma unroll 8
  for (int ch = 0; ch < NCHUNK; ++ch) {
    const float4 p = src[(size_t)ch*1024 + q];
    s.x+=p.x; s.y+=p.y; s.z+=p.z; s.w+=p.w;
  }
  *(reinterpret_cast<float4*>(ws + CMOFF) + (size_t)m*1024 + q) = s;
}

/* ---- merged: bid<64 -> U_raw = Wv @ T  |  bid>=64 -> power iteration 1/sigma ---- */
__global__ __launch_bounds__(256) void k_su(const float* __restrict__ Wv, float* __restrict__ ws)
{
  __shared__ float smA[64][64];
  __shared__ float smB[64][64];
  const int bid = blockIdx.x;
  const int t = threadIdx.x;
  if (bid < 64) {
    const int b = bid >> 3, rt = bid & 7;
    const float* T = ws + CMOFF + (size_t)(b*3+2)*4096;
    for (int q = t; q < 1024; q += 256)
      *(reinterpret_cast<float4*>(&smB[0][0]) + q) = *(reinterpret_cast<const float4*>(T) + q);
    for (int q = t; q < 1024; q += 256) {
      const int row = q >> 4;
      const int c4  = (q & 15) * 4;
      const float4 wv = *reinterpret_cast<const float4*>(&Wv[(size_t)(rt*64+row)*64 + c4]);
      smA[c4+0][row]=wv.x; smA[c4+1][row]=wv.y; smA[c4+2][row]=wv.z; smA[c4+3][row]=wv.w;
    }
    __syncthreads();
    const int ti = t >> 4, tj = t & 15;
    float acc[4][4] = {};
    #pragma unroll
    for (int c = 0; c < 64; ++c) {
      const float4 a  = *reinterpret_cast<const float4*>(&smA[c][ti*4]);
      const float4 bb = *reinterpret_cast<const float4*>(&smB[c][tj*4]);
      FMA16(a, bb)
    }
    #pragma unroll
    for (int i = 0; i < 4; ++i) {
      float4 o; o.x = acc[i][0]; o.y = acc[i][1]; o.z = acc[i][2]; o.w = acc[i][3];
      *reinterpret_cast<float4*>(&ws[UOFF + ((size_t)b*512 + rt*64 + ti*4+i)*64 + tj*4]) = o;
    }
  } else {
    const int b = bid - 64;
    float* vsh = &smA[0][0];
    float* ush = &smA[1][0];
    const float* Cf = ws + CMOFF + (size_t)(b*3+0)*4096;
    const float* Cg = ws + CMOFF + (size_t)(b*3+1)*4096;
    float cfr[64], cgr[64];
    if (t < 64) {
      #pragma unroll
      for (int k4 = 0; k4 < 16; ++k4) {
        const float4 fa = *reinterpret_cast<const float4*>(&Cf[t*64 + k4*4]);
        const float4 fc = *reinterpret_cast<const float4*>(&Cg[t*64 + k4*4]);
        cfr[k4*4+0]=fa.x; cfr[k4*4+1]=fa.y; cfr[k4*4+2]=fa.z; cfr[k4*4+3]=fa.w;
        cgr[k4*4+0]=fc.x; cgr[k4*4+1]=fc.y; cgr[k4*4+2]=fc.z; cgr[k4*4+3]=fc.w;
      }
    }
    float vloc = 0.125f;
    if (t < 64) vsh[t] = vloc;
    __syncthreads();
    const int NIT = 16;
    float lambda = 0.f;
    for (int it = 0; it <= NIT; ++it) {
      if (t < 64) {
        float u0=0.f,u1=0.f,u2=0.f,u3=0.f;
        #pragma unroll
        for (int j4 = 0; j4 < 16; ++j4) {
          const float4 vq = *reinterpret_cast<const float4*>(&vsh[j4*4]);
          u0 += cfr[j4*4+0]*vq.x; u1 += cfr[j4*4+1]*vq.y;
          u2 += cfr[j4*4+2]*vq.z; u3 += cfr[j4*4+3]*vq.w;
        }
        ush[t] = (u0+u1)+(u2+u3);
      }
      __syncthreads();
      float w = 0.f;
      if (t < 64) {
        float w0=0.f,w1=0.f,w2=0.f,w3=0.f;
        #pragma unroll
        for (int j4 = 0; j4 < 16; ++j4) {
          const float4 uq = *reinterpret_cast<const float4*>(&ush[j4*4]);
          w0 += cgr[j4*4+0]*uq.x; w1 += cgr[j4*4+1]*uq.y;
          w2 += cgr[j4*4+2]*uq.z; w3 += cgr[j4*4+3]*uq.w;
        }
        w = (w0+w1)+(w2+w3);
      }
      if (it == NIT) {
        if (t < 64) {
          float num = vloc * w;
          #pragma unroll
          for (int off = 32; off > 0; off >>= 1) num += __shfl_xor(num, off);
          lambda = num;
        }
      } else {
        if (t < 64) {
          float n2 = w*w;
          #pragma unroll
          for (int off = 32; off > 0; off >>= 1) n2 += __shfl_xor(n2, off);
          const float rn = rsqrtf(fmaxf(n2, 1e-30f));
          vloc = w * rn;
        }
        __syncthreads();
        if (t < 64) vsh[t] = vloc;
        __syncthreads();
      }
    }
    if (t == 0) ws[ISOFF + b] = rsqrtf(fmaxf(lambda, 1e-30f));
  }
}

/* ---- out = isig*(U_raw @ F) + bv + x ---- */
__global__ __launch_bounds__(256) void k_final(
    const float* __restrict__ x, const float* __restrict__ bv,
    const float* __restrict__ gamma_f, const float* __restrict__ beta_f,
    float* __restrict__ out, const float* __restrict__ ws)
{
  __shared__ float Ut[64][64];
  __shared__ float Fl[64][64];
  __shared__ float scF[64], sfF[64];
  const int nt = blockIdx.x, ot = blockIdx.y, b = blockIdx.z;
  const int t = threadIdx.x;
  if (t < 64) {
    const float s  = ws[SPOFF + t*2 + 0];
    const float s2 = ws[SPOFF + t*2 + 1];
    const float mean = s*(1.0f/NCOL);
    const float var  = s2*(1.0f/NCOL) - mean*mean;
    const float sc = gamma_f[t] * rsqrtf(var + EPS);
    scF[t] = sc; sfF[t] = beta_f[t] - mean*sc;
  }
  for (int q = t; q < 1024; q += 256) {
    const int row = q >> 4, k4 = (q & 15)*4;
    const float4 uv = *reinterpret_cast<const float4*>(
        &ws[UOFF + ((size_t)b*512 + ot*64 + row)*64 + k4]);
    Ut[k4+0][row]=uv.x; Ut[k4+1][row]=uv.y; Ut[k4+2][row]=uv.z; Ut[k4+3][row]=uv.w;
  }
  for (int q = t; q < 1024; q += 256) {
    const int k = q >> 4, c4 = (q & 15)*4;
    const float4 yv = *reinterpret_cast<const float4*>(
        &ws[YOFF + (size_t)k*NCOL + b*1024 + nt*64 + c4]);
    Fl[k][c4+0]=yv.x; Fl[k][c4+1]=yv.y; Fl[k][c4+2]=yv.z; Fl[k][c4+3]=yv.w;
  }
  __syncthreads();
  for (int q = t; q < 1024; q += 256) {
    const int k = q >> 4, c4 = (q & 15)*4;
    const float s = scF[k], f = sfF[k];
    Fl[k][c4+0]=fmaxf(s*Fl[k][c4+0]+f,0.f); Fl[k][c4+1]=fmaxf(s*Fl[k][c4+1]+f,0.f);
    Fl[k][c4+2]=fmaxf(s*Fl[k][c4+2]+f,0.f); Fl[k][c4+3]=fmaxf(s*Fl[k][c4+3]+f,0.f);
  }
  __syncthreads();
  const float isig = ws[ISOFF + b];
  const int ti = t >> 4, tj = t & 15;
  float acc[4][4] = {};
  #pragma unroll
  for (int k = 0; k < 64; ++k) {
    const float4 a  = *reinterpret_cast<const float4*>(&Ut[k][ti*4]);
    const float4 bb = *reinterpret_cast<const float4*>(&Fl[k][tj*4]);
    FMA16(a, bb)
  }
  #pragma unroll
  for (int i = 0; i < 4; ++i) {
    const int oc = ot*64 + ti*4 + i;
    const float bvv = bv[oc];
    const size_t base = ((size_t)b*C_ + oc)*HW_ + nt*64 + tj*4;
    const float4 xv = *reinterpret_cast<const float4*>(&x[base]);
    float4 o;
    o.x = acc[i][0]*isig+bvv+xv.x; o.y = acc[i][1]*isig+bvv+xv.y;
    o.z = acc[i][2]*isig+bvv+xv.z; o.w = acc[i][3]*isig+bvv+xv.w;
    *reinterpret_cast<float4*>(&out[base]) = o;
  }
}

extern "C" void kernel_launch(void* const* d_in, const int* in_sizes, int n_in,
                              void* d_out, int out_size, void* d_ws, size_t ws_size,
                              hipStream_t stream) {
  (void)in_sizes; (void)n_in; (void)out_size; (void)ws_size;
  const float* x       = (const float*)d_in[0];
  const float* Wf      = (const float*)d_in[1];
  const float* bf      = (const float*)d_in[2];
  const float* gamma_f = (const float*)d_in[3];
  const float* beta_f  = (const float*)d_in[4];
  const float* Wg      = (const float*)d_in[5];
  const float* bg      = (const float*)d_in[6];
  const float* gamma_g = (const float*)d_in[7];
  const float* beta_g  = (const float*)d_in[8];
  const float* Wh      = (const float*)d_in[9];
  const float* bh      = (const float*)d_in[10];
  const float* Wv      = (const float*)d_in[11];
  const float* bv      = (const float*)d_in[12];
  float* out = (float*)d_out;
  float* ws  = (float*)d_ws;

  k_prep   <<<96,              256, 0, stream>>>(Wf, Wg, Wh, ws);
  k_conv   <<<256,             256, 0, stream>>>(x, bf, bg, bh, ws);
  k_stats  <<<128,             256, 0, stream>>>(ws);
  k_cpart  <<<dim3(NCHUNK,8),  256, 0, stream>>>(gamma_f, beta_f, gamma_g, beta_g, ws);
  k_creduce<<<dim3(4,24),      256, 0, stream>>>(ws);
  k_su     <<<72,              256, 0, stream>>>(Wv, ws);
  k_final  <<<dim3(16,8,8),    256, 0, stream>>>(x, bv, gamma_f, beta_f, out, ws);
}